// Round 4
// baseline (1896.526 us; speedup 1.0000x reference)
//
#include <hip/hip_runtime.h>
#include <math.h>

#define BB 2048
#define SS 96
#define DD 7
#define HH 64
#define H2 16
#define PAD 65   // loB stride
#define TPAD 97  // tkT stride

__device__ __forceinline__ float sigm(float x) { return 1.0f / (1.0f + __expf(-x)); }
__device__ __forceinline__ float tanh_f(float x) { return 1.0f - 2.0f / (__expf(2.0f * x) + 1.0f); }
// broadcast lane l of v to all lanes via SGPR (VALU pipe, not LDS)
__device__ __forceinline__ float rl(float v, int l) {
    return __int_as_float(__builtin_amdgcn_readlane(__float_as_int(v), l));
}

// One block per batch element. 512 threads = 8 waves.
// LDS: loB[96*65] persistent + R2[14080] phase-reused = 81,280 B -> 2 blocks/CU.
// VGPR cap 128 via launch_bounds(512,2) (observed: 2nd arg acts as min blocks/CU).
__global__ __launch_bounds__(512, 2) void k_fused(
    const float* __restrict__ x,
    const float* __restrict__ fv_w, const float* __restrict__ fv_b,
    const float* __restrict__ fk_w, const float* __restrict__ fk_b,
    const float* __restrict__ fq_w, const float* __restrict__ fq_b,
    const float* __restrict__ l1f_wih, const float* __restrict__ l1f_whh,
    const float* __restrict__ l1f_bih, const float* __restrict__ l1f_bhh,
    const float* __restrict__ l1b_wih, const float* __restrict__ l1b_whh,
    const float* __restrict__ l1b_bih, const float* __restrict__ l1b_bhh,
    const float* __restrict__ tv_w, const float* __restrict__ tv_b,
    const float* __restrict__ tk_w, const float* __restrict__ tk_b,
    const float* __restrict__ tq_w, const float* __restrict__ tq_b,
    const float* __restrict__ l2_wih, const float* __restrict__ l2_whh,
    const float* __restrict__ l2_bih, const float* __restrict__ l2_bhh,
    const float* __restrict__ fc_w, const float* __restrict__ fc_b,
    float* __restrict__ out)
{
    __shared__ float loB[SS * PAD];   // lo, then 'to' (row-wise overwrite)
    __shared__ float R2[14080];       // phase-reused region

    const int b = blockIdx.x, t = threadIdx.x;
    const int lane = t & 63, w = t >> 6;

    // ---------- region aliases ----------
    float* fas  = R2;                 // [672]   fa (feat out, L1 in)
    float* xs   = R2 + 672;           // feat scratch
    float* vs   = R2 + 1344;
    float* ks   = R2 + 2016;
    float* qs   = R2 + 2688;
    float* att  = R2 + 3360;          // [49]
    float* wvS  = R2 + 3409; float* wkS = R2 + 3458; float* wqS = R2 + 3507;
    float* bvS  = R2 + 3556; float* bkS = R2 + 3563; float* bqS = R2 + 3570;
    float* hbuf = R2 + 672;           // [2][64] (xs dead by then)
    float* hs   = R2 + 800;           // [2][96][64] = 12288
    float* tkT  = R2;                 // [64*97]=6208 (fas/hbuf dead)
    float* tvB  = R2 + 6208;          // [96*65]=6240 (hs dead)
    float* hsb  = R2 + 12448;         // [96*17]=1632

    // =================== Phase F: feature attention ===================
    {
        const float* xb = x + (size_t)b * SS * DD;
        for (int idx = t; idx < SS * DD; idx += 512) xs[idx] = xb[idx];
        if (t < DD * DD) { wvS[t] = fv_w[t]; wkS[t] = fk_w[t]; wqS[t] = fq_w[t]; }
        if (t < DD)      { bvS[t] = fv_b[t]; bkS[t] = fk_b[t]; bqS[t] = fq_b[t]; }
        __syncthreads();
        for (int idx = t; idx < SS * DD; idx += 512) {
            int s = idx / DD, j = idx % DD;
            float a = bvS[j];
            #pragma unroll
            for (int i = 0; i < DD; i++) a += xs[s * DD + i] * wvS[j * DD + i];
            vs[idx] = a;
        }
        __syncthreads();
        for (int idx = t; idx < SS * DD; idx += 512) {
            int s = idx / DD, j = idx % DD;
            float a = bkS[j];
            #pragma unroll
            for (int i = 0; i < DD; i++) a += (xs[s * DD + i] + vs[s * DD + i]) * wkS[j * DD + i];
            ks[idx] = a;
        }
        __syncthreads();
        for (int idx = t; idx < SS * DD; idx += 512) {
            int s = idx / DD, j = idx % DD;
            float a = bqS[j];
            #pragma unroll
            for (int i = 0; i < DD; i++) a += (xs[s * DD + i] + ks[s * DD + i]) * wqS[j * DD + i];
            qs[idx] = a;
        }
        __syncthreads();
        if (t < DD * DD) {
            int i = t / DD, j = t % DD;
            float a = 0.0f;
            for (int s = 0; s < SS; s++) a += qs[s * DD + i] * ks[s * DD + j];
            att[t] = a;
        }
        __syncthreads();
        if (t < DD) {
            float m = -1e30f;
            #pragma unroll
            for (int j = 0; j < DD; j++) m = fmaxf(m, att[t * DD + j]);
            float e[DD]; float sum = 0.0f;
            #pragma unroll
            for (int j = 0; j < DD; j++) { e[j] = __expf(att[t * DD + j] - m); sum += e[j]; }
            float inv = 1.0f / sum;
            #pragma unroll
            for (int j = 0; j < DD; j++) att[t * DD + j] = e[j] * inv;
        }
        __syncthreads();
        for (int idx = t; idx < SS * DD; idx += 512) {
            int s = idx / DD, j = idx % DD;
            float a = xs[idx];
            #pragma unroll
            for (int i = 0; i < DD; i++) a += vs[s * DD + i] * att[i * DD + j];
            fas[idx] = tanh_f(a);      // note: fas disjoint from xs/vs/att scratch
        }
    }

    // =================== Phase L1: BiLSTM, 1 barrier/step ===================
    // waves 0-3: forward dir; waves 4-7: backward. Wave owns 16 units;
    // lane = 16*gate + unit_in_group. Gate exchange via __shfl (in-wave).
    {
        const int dir = w >> 2, wq4 = w & 3;
        const int u = lane & 15;           // unit within group
        const int gi = lane >> 4;          // gate index (i,f,g,o)
        const int unit = 16 * wq4 + u;
        const int row = 64 * gi + unit;
        const float* whh = dir ? l1b_whh : l1f_whh;
        const float* wih = dir ? l1b_wih : l1f_wih;
        float wr[HH];
        #pragma unroll
        for (int j = 0; j < HH; j++) wr[j] = whh[row * HH + j];
        float wx[DD];
        #pragma unroll
        for (int i = 0; i < DD; i++) wx[i] = wih[row * DD + i];
        const float bias = dir ? (l1b_bih[row] + l1b_bhh[row])
                               : (l1f_bih[row] + l1f_bhh[row]);
        if (t < 128) hbuf[t] = 0.0f;
        __syncthreads();   // fas ready + hbuf init

        float c = 0.0f;
        for (int step = 0; step < SS; step++) {
            const int s = dir ? (SS - 1 - step) : step;
            float freg = fas[s * DD + (lane < DD ? lane : DD - 1)];
            float a = bias;
            #pragma unroll
            for (int i = 0; i < DD; i++) a += rl(freg, i) * wx[i];
            float hreg = hbuf[dir * HH + lane];
            float b0 = 0.f, b1 = 0.f, b2 = 0.f, b3 = 0.f;
            #pragma unroll
            for (int j = 0; j < HH; j += 4) {
                b0 += rl(hreg, j)     * wr[j];
                b1 += rl(hreg, j + 1) * wr[j + 1];
                b2 += rl(hreg, j + 2) * wr[j + 2];
                b3 += rl(hreg, j + 3) * wr[j + 3];
            }
            a += (b0 + b1) + (b2 + b3);
            float iv = __shfl(a, u);
            float fv = __shfl(a, 16 + u);
            float gv = __shfl(a, 32 + u);
            float ov = __shfl(a, 48 + u);
            c = sigm(fv) * c + sigm(iv) * tanh_f(gv);
            float h = sigm(ov) * tanh_f(c);
            if (gi == 0) {
                hbuf[dir * HH + unit] = h;
                hs[dir * (SS * HH) + s * HH + unit] = h;
            }
            __syncthreads();
        }
    }

    // transition: loB = 0.5*(hf+hb), padded
    for (int idx = t; idx < SS * HH; idx += 512) {
        int s = idx >> 6, d = idx & 63;
        loB[s * PAD + d] = 0.5f * (hs[idx] + hs[SS * HH + idx]);
    }
    __syncthreads();

    // =================== Phase A: tv (waves 0-1), tk (waves 2-3) ===================
    if (w < 4) {
        const float* wmat = (w < 2) ? tv_w : tk_w;
        const float* bvec = (w < 2) ? tv_b : tk_b;
        const int srow = (w & 1) * 64 + lane;
        if (srow < SS) {
            float lorow[HH];
            #pragma unroll
            for (int d = 0; d < HH; d++) lorow[d] = loB[srow * PAD + d];
            for (int j = 0; j < HH; j++) {
                float a0 = 0.f, a1 = 0.f, a2 = 0.f, a3 = 0.f;
                #pragma unroll
                for (int d = 0; d < HH; d += 4) {
                    a0 += lorow[d]     * wmat[j * HH + d];
                    a1 += lorow[d + 1] * wmat[j * HH + d + 1];
                    a2 += lorow[d + 2] * wmat[j * HH + d + 2];
                    a3 += lorow[d + 3] * wmat[j * HH + d + 3];
                }
                float a = bvec[j] + (a0 + a1) + (a2 + a3);
                if (w < 2) tvB[srow * PAD + j] = a;
                else       tkT[j * TPAD + srow] = a;
            }
        }
    }
    // all waves: wq -> regs (lane f holds tq_w[f][:])
    float wq[HH];
    #pragma unroll
    for (int e = 0; e < HH; e++) wq[e] = tq_w[lane * HH + e];
    const float qbias = tq_b[lane];
    __syncthreads();

    // =================== Phase B: q -> scores -> softmax -> PV -> 'to' ===================
    for (int gi2 = 0; gi2 < 3; gi2++) {
        const int i0 = 4 * (w + 8 * gi2);
        float lr0 = loB[(i0 + 0) * PAD + lane];
        float lr1 = loB[(i0 + 1) * PAD + lane];
        float lr2 = loB[(i0 + 2) * PAD + lane];
        float lr3 = loB[(i0 + 3) * PAD + lane];
        float q0 = qbias, q1 = qbias, q2 = qbias, q3 = qbias;
        #pragma unroll
        for (int e = 0; e < HH; e++) {
            float we = wq[e];
            q0 += rl(lr0, e) * we;
            q1 += rl(lr1, e) * we;
            q2 += rl(lr2, e) * we;
            q3 += rl(lr3, e) * we;
        }
        const int p2i = 64 + (lane & 31);
        float a10 = 0.f, a11 = 0.f, a12 = 0.f, a13 = 0.f;
        float a20 = 0.f, a21 = 0.f, a22 = 0.f, a23 = 0.f;
        for (int f = 0; f < HH; f++) {
            float t1 = tkT[f * TPAD + lane];
            float t2 = tkT[f * TPAD + p2i];
            float s0 = rl(q0, f), s1 = rl(q1, f), s2 = rl(q2, f), s3 = rl(q3, f);
            a10 += s0 * t1; a20 += s0 * t2;
            a11 += s1 * t1; a21 += s1 * t2;
            a12 += s2 * t1; a22 += s2 * t2;
            a13 += s3 * t1; a23 += s3 * t2;
        }
        float p10, p11, p12, p13, p20, p21, p22, p23;
        {
            float m, s, e1, e2, ivv;
            m = fmaxf(a10, a20);
            #pragma unroll
            for (int o = 32; o; o >>= 1) m = fmaxf(m, __shfl_xor(m, o));
            e1 = __expf(a10 - m); e2 = __expf(a20 - m);
            s = e1 + ((lane < 32) ? e2 : 0.0f);
            #pragma unroll
            for (int o = 32; o; o >>= 1) s += __shfl_xor(s, o);
            ivv = 1.0f / s; p10 = e1 * ivv; p20 = e2 * ivv;

            m = fmaxf(a11, a21);
            #pragma unroll
            for (int o = 32; o; o >>= 1) m = fmaxf(m, __shfl_xor(m, o));
            e1 = __expf(a11 - m); e2 = __expf(a21 - m);
            s = e1 + ((lane < 32) ? e2 : 0.0f);
            #pragma unroll
            for (int o = 32; o; o >>= 1) s += __shfl_xor(s, o);
            ivv = 1.0f / s; p11 = e1 * ivv; p21 = e2 * ivv;

            m = fmaxf(a12, a22);
            #pragma unroll
            for (int o = 32; o; o >>= 1) m = fmaxf(m, __shfl_xor(m, o));
            e1 = __expf(a12 - m); e2 = __expf(a22 - m);
            s = e1 + ((lane < 32) ? e2 : 0.0f);
            #pragma unroll
            for (int o = 32; o; o >>= 1) s += __shfl_xor(s, o);
            ivv = 1.0f / s; p12 = e1 * ivv; p22 = e2 * ivv;

            m = fmaxf(a13, a23);
            #pragma unroll
            for (int o = 32; o; o >>= 1) m = fmaxf(m, __shfl_xor(m, o));
            e1 = __expf(a13 - m); e2 = __expf(a23 - m);
            s = e1 + ((lane < 32) ? e2 : 0.0f);
            #pragma unroll
            for (int o = 32; o; o >>= 1) s += __shfl_xor(s, o);
            ivv = 1.0f / s; p13 = e1 * ivv; p23 = e2 * ivv;
        }
        float o0 = 0.f, o1 = 0.f, o2 = 0.f, o3 = 0.f;
        for (int P = 0; P < 64; P++) {
            float tvv = tvB[P * PAD + lane];
            o0 += rl(p10, P) * tvv;
            o1 += rl(p11, P) * tvv;
            o2 += rl(p12, P) * tvv;
            o3 += rl(p13, P) * tvv;
        }
        for (int P = 0; P < 32; P++) {
            float tvv = tvB[(64 + P) * PAD + lane];
            o0 += rl(p20, P) * tvv;
            o1 += rl(p21, P) * tvv;
            o2 += rl(p22, P) * tvv;
            o3 += rl(p23, P) * tvv;
        }
        loB[(i0 + 0) * PAD + lane] = tanh_f(o0);
        loB[(i0 + 1) * PAD + lane] = tanh_f(o1);
        loB[(i0 + 2) * PAD + lane] = tanh_f(o2);
        loB[(i0 + 3) * PAD + lane] = tanh_f(o3);
    }
    __syncthreads();

    // =================== Phase C: xg2 = to @ l2_wih^T + biases -> tvB ===================
    if (w < 2) {
        const int srow = w * 64 + lane;
        if (srow < SS) {
            float toRow[HH];
            #pragma unroll
            for (int d = 0; d < HH; d++) toRow[d] = loB[srow * PAD + d];
            for (int gg = 0; gg < HH; gg++) {
                float a0 = 0.f, a1 = 0.f, a2 = 0.f, a3 = 0.f;
                #pragma unroll
                for (int d = 0; d < HH; d += 4) {
                    a0 += toRow[d]     * l2_wih[gg * HH + d];
                    a1 += toRow[d + 1] * l2_wih[gg * HH + d + 1];
                    a2 += toRow[d + 2] * l2_wih[gg * HH + d + 2];
                    a3 += toRow[d + 3] * l2_wih[gg * HH + d + 3];
                }
                tvB[srow * PAD + gg] = l2_bih[gg] + l2_bhh[gg] + (a0 + a1) + (a2 + a3);
            }
        }
    }
    __syncthreads();

    // =================== Phase D: LSTM2 scan (wave 0) ===================
    if (t < 64) {
        float whr[H2];
        #pragma unroll
        for (int j = 0; j < H2; j++) whr[j] = l2_whh[lane * H2 + j];
        const int myi = lane & 15;
        float h = 0.0f, c = 0.0f;
        for (int s = 0; s < SS; s++) {
            float a = tvB[s * PAD + lane];
            #pragma unroll
            for (int j = 0; j < H2; j++) a += rl(h, j) * whr[j];
            float iv = __shfl(a, myi);
            float fv = __shfl(a, H2 + myi);
            float gv = __shfl(a, 2 * H2 + myi);
            float ov = __shfl(a, 3 * H2 + myi);
            c = sigm(fv) * c + sigm(iv) * tanh_f(gv);
            h = sigm(ov) * tanh_f(c);
            if (lane < H2) hsb[s * 17 + lane] = h;
        }
    }
    __syncthreads();

    // =================== Phase E: fc ===================
    if (w < 2) {
        const int srow = w * 64 + lane;
        if (srow < SS) {
            float hreg[H2];
            #pragma unroll
            for (int j = 0; j < H2; j++) hreg[j] = hsb[srow * 17 + j];
            float* op = out + (size_t)b * SS * DD + srow * DD;
            for (int d = 0; d < DD; d++) {
                float a = fc_b[d];
                #pragma unroll
                for (int j = 0; j < H2; j++) a += hreg[j] * fc_w[d * H2 + j];
                op[d] = a;
            }
        }
    }
}

extern "C" void kernel_launch(void* const* d_in, const int* in_sizes, int n_in,
                              void* d_out, int out_size, void* d_ws, size_t ws_size,
                              hipStream_t stream) {
    const float* x     = (const float*)d_in[0];
    const float* fv_w  = (const float*)d_in[1];
    const float* fv_b  = (const float*)d_in[2];
    const float* fk_w  = (const float*)d_in[3];
    const float* fk_b  = (const float*)d_in[4];
    const float* fq_w  = (const float*)d_in[5];
    const float* fq_b  = (const float*)d_in[6];
    const float* l1f_wih = (const float*)d_in[7];
    const float* l1f_whh = (const float*)d_in[8];
    const float* l1f_bih = (const float*)d_in[9];
    const float* l1f_bhh = (const float*)d_in[10];
    const float* l1b_wih = (const float*)d_in[11];
    const float* l1b_whh = (const float*)d_in[12];
    const float* l1b_bih = (const float*)d_in[13];
    const float* l1b_bhh = (const float*)d_in[14];
    const float* tv_w  = (const float*)d_in[15];
    const float* tv_b  = (const float*)d_in[16];
    const float* tk_w  = (const float*)d_in[17];
    const float* tk_b  = (const float*)d_in[18];
    const float* tq_w  = (const float*)d_in[19];
    const float* tq_b  = (const float*)d_in[20];
    const float* l2_wih = (const float*)d_in[21];
    const float* l2_whh = (const float*)d_in[22];
    const float* l2_bih = (const float*)d_in[23];
    const float* l2_bhh = (const float*)d_in[24];
    const float* fc_w  = (const float*)d_in[25];
    const float* fc_b  = (const float*)d_in[26];

    k_fused<<<BB, 512, 0, stream>>>(x,
        fv_w, fv_b, fk_w, fk_b, fq_w, fq_b,
        l1f_wih, l1f_whh, l1f_bih, l1f_bhh,
        l1b_wih, l1b_whh, l1b_bih, l1b_bhh,
        tv_w, tv_b, tk_w, tk_b, tq_w, tq_b,
        l2_wih, l2_whh, l2_bih, l2_bhh, fc_w, fc_b,
        (float*)d_out);
}

// Round 5
// 1767.250 us; speedup vs baseline: 1.0732x; 1.0732x over previous
//
#include <hip/hip_runtime.h>
#include <math.h>

#define BB 2048
#define SS 96
#define DD 7
#define HH 64
#define H2 16
#define PAD 65   // [96][65] padded tiles
#define TPAD 97  // tkT [64][97]

__device__ __forceinline__ float sigm(float x) { return 1.0f / (1.0f + __expf(-x)); }
__device__ __forceinline__ float tanh_f(float x) { return 1.0f - 2.0f / (__expf(2.0f * x) + 1.0f); }
// broadcast lane l of v to all lanes via SGPR (VALU pipe, not LDS)
__device__ __forceinline__ float rl(float v, int l) {
    return __int_as_float(__builtin_amdgcn_readlane(__float_as_int(v), l));
}

// ---------------- Kernel 1: feature attention ----------------
__global__ __launch_bounds__(256) void k_feat(
    const float* __restrict__ x,
    const float* __restrict__ fv_w, const float* __restrict__ fv_b,
    const float* __restrict__ fk_w, const float* __restrict__ fk_b,
    const float* __restrict__ fq_w, const float* __restrict__ fq_b,
    float* __restrict__ fa_out)
{
    __shared__ float xs[SS * DD], vs[SS * DD], ks[SS * DD], qs[SS * DD];
    __shared__ float att[DD * DD];
    __shared__ float wv[DD * DD], wk[DD * DD], wq[DD * DD];
    __shared__ float bv[DD], bk[DD], bq[DD];
    const int b = blockIdx.x, t = threadIdx.x;
    const float* xb = x + (size_t)b * SS * DD;

    for (int idx = t; idx < SS * DD; idx += 256) xs[idx] = xb[idx];
    if (t < DD * DD) { wv[t] = fv_w[t]; wk[t] = fk_w[t]; wq[t] = fq_w[t]; }
    if (t < DD)      { bv[t] = fv_b[t]; bk[t] = fk_b[t]; bq[t] = fq_b[t]; }
    __syncthreads();

    for (int idx = t; idx < SS * DD; idx += 256) {
        int s = idx / DD, j = idx % DD;
        float a = bv[j];
        #pragma unroll
        for (int i = 0; i < DD; i++) a += xs[s * DD + i] * wv[j * DD + i];
        vs[idx] = a;
    }
    __syncthreads();
    for (int idx = t; idx < SS * DD; idx += 256) {
        int s = idx / DD, j = idx % DD;
        float a = bk[j];
        #pragma unroll
        for (int i = 0; i < DD; i++) a += (xs[s * DD + i] + vs[s * DD + i]) * wk[j * DD + i];
        ks[idx] = a;
    }
    __syncthreads();
    for (int idx = t; idx < SS * DD; idx += 256) {
        int s = idx / DD, j = idx % DD;
        float a = bq[j];
        #pragma unroll
        for (int i = 0; i < DD; i++) a += (xs[s * DD + i] + ks[s * DD + i]) * wq[j * DD + i];
        qs[idx] = a;
    }
    __syncthreads();
    if (t < DD * DD) {
        int i = t / DD, j = t % DD;
        float a = 0.0f;
        for (int s = 0; s < SS; s++) a += qs[s * DD + i] * ks[s * DD + j];
        att[t] = a;
    }
    __syncthreads();
    if (t < DD) {
        float m = -1e30f;
        #pragma unroll
        for (int j = 0; j < DD; j++) m = fmaxf(m, att[t * DD + j]);
        float e[DD]; float sum = 0.0f;
        #pragma unroll
        for (int j = 0; j < DD; j++) { e[j] = __expf(att[t * DD + j] - m); sum += e[j]; }
        float inv = 1.0f / sum;
        #pragma unroll
        for (int j = 0; j < DD; j++) att[t * DD + j] = e[j] * inv;
    }
    __syncthreads();
    for (int idx = t; idx < SS * DD; idx += 256) {
        int s = idx / DD, j = idx % DD;
        float a = xs[idx];
        #pragma unroll
        for (int i = 0; i < DD; i++) a += vs[s * DD + i] * att[i * DD + j];
        fa_out[(size_t)b * SS * DD + idx] = tanh_f(a);
    }
}

// ---------------- Kernel 2: bidirectional LSTM, 1 barrier/step ----------------
// waves 0-3: forward, waves 4-7: backward. Wave owns 16 units; lane = 16*gate+u.
// Gate exchange in-wave via __shfl; h broadcast via 1 LDS read + readlane.
__global__ __launch_bounds__(512, 2) void k_bilstm(
    const float* __restrict__ fa,
    const float* __restrict__ wih_f, const float* __restrict__ whh_f,
    const float* __restrict__ bih_f, const float* __restrict__ bhh_f,
    const float* __restrict__ wih_b, const float* __restrict__ whh_b,
    const float* __restrict__ bih_b, const float* __restrict__ bhh_b,
    float* __restrict__ lo_out)
{
    __shared__ float fas[SS * DD];        // 672
    __shared__ float hbuf[2][HH];         // 128
    __shared__ float hs[2][SS][HH];       // 12288

    const int b = blockIdx.x, t = threadIdx.x;
    const int lane = t & 63, w = t >> 6;
    const int dir = w >> 2, wq4 = w & 3;
    const int u = lane & 15;              // unit within wave's group
    const int gi = lane >> 4;             // gate (i,f,g,o)
    const int unit = 16 * wq4 + u;
    const int row = 64 * gi + unit;

    for (int idx = t; idx < SS * DD; idx += 512) fas[idx] = fa[(size_t)b * SS * DD + idx];

    const float* whh = dir ? whh_b : whh_f;
    const float* wih = dir ? wih_b : wih_f;
    float wr[HH];
    #pragma unroll
    for (int j = 0; j < HH; j++) wr[j] = whh[row * HH + j];
    float wx[DD];
    #pragma unroll
    for (int i = 0; i < DD; i++) wx[i] = wih[row * DD + i];
    const float bias = dir ? (bih_b[row] + bhh_b[row]) : (bih_f[row] + bhh_f[row]);

    if (t < 128) hbuf[t >> 6][t & 63] = 0.0f;
    __syncthreads();

    float c = 0.0f;
    for (int step = 0; step < SS; step++) {
        const int s = dir ? (SS - 1 - step) : step;
        float freg = fas[s * DD + (lane < DD ? lane : DD - 1)];
        float a = bias;
        #pragma unroll
        for (int i = 0; i < DD; i++) a += rl(freg, i) * wx[i];
        float hreg = hbuf[dir][lane];
        float b0 = 0.f, b1 = 0.f, b2 = 0.f, b3 = 0.f;
        #pragma unroll
        for (int j = 0; j < HH; j += 4) {
            b0 += rl(hreg, j)     * wr[j];
            b1 += rl(hreg, j + 1) * wr[j + 1];
            b2 += rl(hreg, j + 2) * wr[j + 2];
            b3 += rl(hreg, j + 3) * wr[j + 3];
        }
        a += (b0 + b1) + (b2 + b3);
        float iv = __shfl(a, u);
        float fv = __shfl(a, 16 + u);
        float gv = __shfl(a, 32 + u);
        float ov = __shfl(a, 48 + u);
        c = sigm(fv) * c + sigm(iv) * tanh_f(gv);
        float h = sigm(ov) * tanh_f(c);
        if (gi == 0) {
            hbuf[dir][unit] = h;
            hs[dir][s][unit] = h;
        }
        __syncthreads();
    }

    for (int idx = t; idx < SS * HH; idx += 512) {
        int s = idx >> 6, j = idx & 63;
        lo_out[(size_t)b * SS * HH + idx] = 0.5f * (hs[0][s][j] + hs[1][s][j]);
    }
}

// ---------------- Kernel 3: temporal attention + LSTM2 + fc ----------------
// LDS = loB(lo->to->xg2) + tkT(tk^T, later hsb) + tvB(tv) = 74,752 B -> 2 blocks/CU.
__global__ __launch_bounds__(512, 2) void k_temporal(
    const float* __restrict__ lo_g,
    const float* __restrict__ tv_w, const float* __restrict__ tv_b,
    const float* __restrict__ tk_w, const float* __restrict__ tk_b,
    const float* __restrict__ tq_w, const float* __restrict__ tq_b,
    const float* __restrict__ l2_wih, const float* __restrict__ l2_whh,
    const float* __restrict__ l2_bih, const float* __restrict__ l2_bhh,
    const float* __restrict__ fc_w, const float* __restrict__ fc_b,
    float* __restrict__ out)
{
    __shared__ float loB[SS * PAD];    // lo -> 'to' -> xg2 (row-private rewrites)
    __shared__ float tkT[HH * TPAD];   // tk transposed; later hsb[96*17]
    __shared__ float tvB[SS * PAD];    // tv

    const int b = blockIdx.x, t = threadIdx.x;
    const int lane = t & 63, w = t >> 6;
    float* hsb = tkT;                  // overlay: tkT dead after Phase B

    const float4* lo_src = (const float4*)(lo_g + (size_t)b * SS * HH);
    #pragma unroll
    for (int k = 0; k < 3; k++) {
        int idx4 = t + 512 * k;
        float4 v = lo_src[idx4];
        int s = idx4 >> 4, d = (idx4 & 15) * 4;
        loB[s * PAD + d]     = v.x;
        loB[s * PAD + d + 1] = v.y;
        loB[s * PAD + d + 2] = v.z;
        loB[s * PAD + d + 3] = v.w;
    }
    __syncthreads();

    // ---- Phase A: tv (waves 0-1), tk (waves 2-3), SGPR weights ----
    if (w < 4) {
        const float* wmat = (w < 2) ? tv_w : tk_w;
        const float* bvec = (w < 2) ? tv_b : tk_b;
        const int srow = (w & 1) * 64 + lane;
        if (srow < SS) {
            float lorow[HH];
            #pragma unroll
            for (int d = 0; d < HH; d++) lorow[d] = loB[srow * PAD + d];
            for (int j = 0; j < HH; j++) {
                float a0 = 0.f, a1 = 0.f, a2 = 0.f, a3 = 0.f;
                #pragma unroll
                for (int d = 0; d < HH; d += 4) {
                    a0 += lorow[d]     * wmat[j * HH + d];
                    a1 += lorow[d + 1] * wmat[j * HH + d + 1];
                    a2 += lorow[d + 2] * wmat[j * HH + d + 2];
                    a3 += lorow[d + 3] * wmat[j * HH + d + 3];
                }
                float a = bvec[j] + (a0 + a1) + (a2 + a3);
                if (w < 2) tvB[srow * PAD + j] = a;
                else       tkT[j * TPAD + srow] = a;
            }
        }
    }
    float wq[HH];
    #pragma unroll
    for (int e = 0; e < HH; e++) wq[e] = tq_w[lane * HH + e];
    const float qbias = tq_b[lane];
    __syncthreads();

    // ---- Phase B: q -> scores -> softmax -> PV -> 'to' (row-private in loB) ----
    for (int gi2 = 0; gi2 < 3; gi2++) {
        const int i0 = 4 * (w + 8 * gi2);
        float lr0 = loB[(i0 + 0) * PAD + lane];
        float lr1 = loB[(i0 + 1) * PAD + lane];
        float lr2 = loB[(i0 + 2) * PAD + lane];
        float lr3 = loB[(i0 + 3) * PAD + lane];
        float q0 = qbias, q1 = qbias, q2 = qbias, q3 = qbias;
        #pragma unroll
        for (int e = 0; e < HH; e++) {
            float we = wq[e];
            q0 += rl(lr0, e) * we;
            q1 += rl(lr1, e) * we;
            q2 += rl(lr2, e) * we;
            q3 += rl(lr3, e) * we;
        }
        const int p2i = 64 + (lane & 31);
        float a10 = 0.f, a11 = 0.f, a12 = 0.f, a13 = 0.f;
        float a20 = 0.f, a21 = 0.f, a22 = 0.f, a23 = 0.f;
        for (int f = 0; f < HH; f++) {
            float t1 = tkT[f * TPAD + lane];
            float t2 = tkT[f * TPAD + p2i];
            float s0 = rl(q0, f), s1 = rl(q1, f), s2 = rl(q2, f), s3 = rl(q3, f);
            a10 += s0 * t1; a20 += s0 * t2;
            a11 += s1 * t1; a21 += s1 * t2;
            a12 += s2 * t1; a22 += s2 * t2;
            a13 += s3 * t1; a23 += s3 * t2;
        }
        float p10, p11, p12, p13, p20, p21, p22, p23;
        {
            float m, s, e1, e2, ivv;
            m = fmaxf(a10, a20);
            #pragma unroll
            for (int o = 32; o; o >>= 1) m = fmaxf(m, __shfl_xor(m, o));
            e1 = __expf(a10 - m); e2 = __expf(a20 - m);
            s = e1 + ((lane < 32) ? e2 : 0.0f);
            #pragma unroll
            for (int o = 32; o; o >>= 1) s += __shfl_xor(s, o);
            ivv = 1.0f / s; p10 = e1 * ivv; p20 = e2 * ivv;

            m = fmaxf(a11, a21);
            #pragma unroll
            for (int o = 32; o; o >>= 1) m = fmaxf(m, __shfl_xor(m, o));
            e1 = __expf(a11 - m); e2 = __expf(a21 - m);
            s = e1 + ((lane < 32) ? e2 : 0.0f);
            #pragma unroll
            for (int o = 32; o; o >>= 1) s += __shfl_xor(s, o);
            ivv = 1.0f / s; p11 = e1 * ivv; p21 = e2 * ivv;

            m = fmaxf(a12, a22);
            #pragma unroll
            for (int o = 32; o; o >>= 1) m = fmaxf(m, __shfl_xor(m, o));
            e1 = __expf(a12 - m); e2 = __expf(a22 - m);
            s = e1 + ((lane < 32) ? e2 : 0.0f);
            #pragma unroll
            for (int o = 32; o; o >>= 1) s += __shfl_xor(s, o);
            ivv = 1.0f / s; p12 = e1 * ivv; p22 = e2 * ivv;

            m = fmaxf(a13, a23);
            #pragma unroll
            for (int o = 32; o; o >>= 1) m = fmaxf(m, __shfl_xor(m, o));
            e1 = __expf(a13 - m); e2 = __expf(a23 - m);
            s = e1 + ((lane < 32) ? e2 : 0.0f);
            #pragma unroll
            for (int o = 32; o; o >>= 1) s += __shfl_xor(s, o);
            ivv = 1.0f / s; p13 = e1 * ivv; p23 = e2 * ivv;
        }
        float o0 = 0.f, o1 = 0.f, o2 = 0.f, o3 = 0.f;
        for (int P = 0; P < 64; P++) {
            float tvv = tvB[P * PAD + lane];
            o0 += rl(p10, P) * tvv;
            o1 += rl(p11, P) * tvv;
            o2 += rl(p12, P) * tvv;
            o3 += rl(p13, P) * tvv;
        }
        for (int P = 0; P < 32; P++) {
            float tvv = tvB[(64 + P) * PAD + lane];
            o0 += rl(p20, P) * tvv;
            o1 += rl(p21, P) * tvv;
            o2 += rl(p22, P) * tvv;
            o3 += rl(p23, P) * tvv;
        }
        loB[(i0 + 0) * PAD + lane] = tanh_f(o0);
        loB[(i0 + 1) * PAD + lane] = tanh_f(o1);
        loB[(i0 + 2) * PAD + lane] = tanh_f(o2);
        loB[(i0 + 3) * PAD + lane] = tanh_f(o3);
    }
    __syncthreads();

    // ---- Phase C: xg2 = to @ l2_wih^T + biases, in-place into loB (row-private) ----
    if (w < 2) {
        const int srow = w * 64 + lane;
        if (srow < SS) {
            float toRow[HH];
            #pragma unroll
            for (int d = 0; d < HH; d++) toRow[d] = loB[srow * PAD + d];
            for (int gg = 0; gg < HH; gg++) {
                float a0 = 0.f, a1 = 0.f, a2 = 0.f, a3 = 0.f;
                #pragma unroll
                for (int d = 0; d < HH; d += 4) {
                    a0 += toRow[d]     * l2_wih[gg * HH + d];
                    a1 += toRow[d + 1] * l2_wih[gg * HH + d + 1];
                    a2 += toRow[d + 2] * l2_wih[gg * HH + d + 2];
                    a3 += toRow[d + 3] * l2_wih[gg * HH + d + 3];
                }
                loB[srow * PAD + gg] = l2_bih[gg] + l2_bhh[gg] + (a0 + a1) + (a2 + a3);
            }
        }
    }
    __syncthreads();

    // ---- Phase D: LSTM2 scan (wave 0), hsb overlays tkT ----
    if (t < 64) {
        float whr[H2];
        #pragma unroll
        for (int j = 0; j < H2; j++) whr[j] = l2_whh[lane * H2 + j];
        const int myi = lane & 15;
        float h = 0.0f, c = 0.0f;
        for (int s = 0; s < SS; s++) {
            float a = loB[s * PAD + lane];
            #pragma unroll
            for (int j = 0; j < H2; j++) a += rl(h, j) * whr[j];
            float iv = __shfl(a, myi);
            float fv = __shfl(a, H2 + myi);
            float gv = __shfl(a, 2 * H2 + myi);
            float ov = __shfl(a, 3 * H2 + myi);
            c = sigm(fv) * c + sigm(iv) * tanh_f(gv);
            h = sigm(ov) * tanh_f(c);
            if (lane < H2) hsb[s * 17 + lane] = h;
        }
    }
    __syncthreads();

    // ---- Phase E: fc ----
    if (w < 2) {
        const int srow = w * 64 + lane;
        if (srow < SS) {
            float hreg[H2];
            #pragma unroll
            for (int j = 0; j < H2; j++) hreg[j] = hsb[srow * 17 + j];
            float* op = out + (size_t)b * SS * DD + srow * DD;
            for (int d = 0; d < DD; d++) {
                float a = fc_b[d];
                #pragma unroll
                for (int j = 0; j < H2; j++) a += hreg[j] * fc_w[d * H2 + j];
                op[d] = a;
            }
        }
    }
}

extern "C" void kernel_launch(void* const* d_in, const int* in_sizes, int n_in,
                              void* d_out, int out_size, void* d_ws, size_t ws_size,
                              hipStream_t stream) {
    const float* x     = (const float*)d_in[0];
    const float* fv_w  = (const float*)d_in[1];
    const float* fv_b  = (const float*)d_in[2];
    const float* fk_w  = (const float*)d_in[3];
    const float* fk_b  = (const float*)d_in[4];
    const float* fq_w  = (const float*)d_in[5];
    const float* fq_b  = (const float*)d_in[6];
    const float* l1f_wih = (const float*)d_in[7];
    const float* l1f_whh = (const float*)d_in[8];
    const float* l1f_bih = (const float*)d_in[9];
    const float* l1f_bhh = (const float*)d_in[10];
    const float* l1b_wih = (const float*)d_in[11];
    const float* l1b_whh = (const float*)d_in[12];
    const float* l1b_bih = (const float*)d_in[13];
    const float* l1b_bhh = (const float*)d_in[14];
    const float* tv_w  = (const float*)d_in[15];
    const float* tv_b  = (const float*)d_in[16];
    const float* tk_w  = (const float*)d_in[17];
    const float* tk_b  = (const float*)d_in[18];
    const float* tq_w  = (const float*)d_in[19];
    const float* tq_b  = (const float*)d_in[20];
    const float* l2_wih = (const float*)d_in[21];
    const float* l2_whh = (const float*)d_in[22];
    const float* l2_bih = (const float*)d_in[23];
    const float* l2_bhh = (const float*)d_in[24];
    const float* fc_w  = (const float*)d_in[25];
    const float* fc_b  = (const float*)d_in[26];

    float* fa = (float*)d_ws;                       // B*S*D floats
    float* lo = fa + (size_t)BB * SS * DD;          // B*S*H floats

    k_feat<<<BB, 256, 0, stream>>>(x, fv_w, fv_b, fk_w, fk_b, fq_w, fq_b, fa);
    k_bilstm<<<BB, 512, 0, stream>>>(fa,
        l1f_wih, l1f_whh, l1f_bih, l1f_bhh,
        l1b_wih, l1b_whh, l1b_bih, l1b_bhh, lo);
    k_temporal<<<BB, 512, 0, stream>>>(lo,
        tv_w, tv_b, tk_w, tk_b, tq_w, tq_b,
        l2_wih, l2_whh, l2_bih, l2_bhh, fc_w, fc_b,
        (float*)d_out);
}